// Round 2
// baseline (19388.399 us; speedup 1.0000x reference)
//
#include <hip/hip_runtime.h>
#include <hip/hip_bf16.h>
#include <math.h>

// ---------------------------------------------------------------------------
// TrafficSeq2Seq: 2-layer GRU encoder (T=256) + 32-step attention decoder.
// Single persistent kernel (plain launch, 64 WGs co-resident by capacity),
// hand-rolled grid barrier. GEMMs via mfma_f32_16x16x32_bf16; decoder in
// split-bf16 (hi/lo) precision.
// ---------------------------------------------------------------------------

#define NWG 64
#define TPB 256

typedef unsigned short u16;
typedef short v8s __attribute__((ext_vector_type(8)));
typedef float v4f __attribute__((ext_vector_type(4)));

#define MFMA_(a,b,c) __builtin_amdgcn_mfma_f32_16x16x32_bf16((a),(b),(c),0,0,0)

__device__ __forceinline__ u16 f2bf(float f){
  unsigned u = __builtin_bit_cast(unsigned, f);
  unsigned r = u + 0x7FFFu + ((u >> 16) & 1u);
  return (u16)(r >> 16);
}
__device__ __forceinline__ float bf2f(u16 s){
  unsigned u = ((unsigned)s) << 16;
  return __builtin_bit_cast(float, u);
}
__device__ __forceinline__ void splitstore(u16* ph, u16* pl, float v){
  u16 h = f2bf(v); ph[0] = h; pl[0] = f2bf(v - bf2f(h));
}
__device__ __forceinline__ float sigm(float x){ return 1.f / (1.f + __expf(-x)); }
__device__ __forceinline__ float tanh_f(float x){
  float ax = fabsf(x);
  float t = __expf(-2.f * ax);
  float r = (1.f - t) / (1.f + t);
  return copysignf(r, x);
}

// fragment load: lane holds M[(r0+(lane&15))*ld + k0 + (lane>>4)*8 .. +8)
__device__ __forceinline__ v8s ldfrag(const u16* base, size_t ld, int r0, int k0){
  int lane = threadIdx.x & 63;
  const u16* p = base + (size_t)(r0 + (lane & 15)) * ld + (size_t)(k0 + ((lane >> 4) << 3));
  return *(const v8s*)p;
}

struct KArgs {
  // inputs (f32)
  const float *x, *target, *eWih_f, *eWhh_f, *ebih, *ebhh;
  const float *dWih0_f, *dWih1_f, *dWhh_f, *dbih, *dbhh;
  const float *aWw_f, *aWb, *aCw_f, *aCb, *o1w_f, *o1b, *o2w_f, *o2b;
  float* out;
  // barrier
  unsigned *flags, *genp;
  // bf16 weights / activations in ws
  u16 *eWih, *eWhh, *xhi, *h0hi, *h1hi, *encout;
  u16 *dWih0h,*dWih0l,*dWih1h,*dWih1l,*dWhhh,*dWhhl;
  u16 *Wwhh,*Wwhl,*Wwxh,*Wwxl,*Wchh,*Wchl,*Wcxh,*Wcxl,*o1wh,*o1wl,*o2wh,*o2wl;
  u16 *xth,*xtl;
  float *preW,*preC;
  u16 *dh0h,*dh0l,*dh1h,*dh1l;
  float *logits,*aw;
  u16 *wcth,*wctl,*xch,*xcl,*o1h,*o1l;
};

// ---- grid barrier: flag-array arrive, WG0 polls, releases gen -------------
__device__ void gbar(unsigned* flags, unsigned* genp, unsigned target){
  __syncthreads();
  __threadfence();
  int wg = blockIdx.x, tid = threadIdx.x;
  if (wg == 0){
    if (tid > 0 && tid < NWG){
      while (__hip_atomic_load(&flags[tid], __ATOMIC_ACQUIRE, __HIP_MEMORY_SCOPE_AGENT) < target)
        __builtin_amdgcn_s_sleep(2);
    }
    __syncthreads();
    if (tid == 0)
      __hip_atomic_store(genp, target, __ATOMIC_RELEASE, __HIP_MEMORY_SCOPE_AGENT);
  } else {
    if (tid == 0){
      __hip_atomic_store(&flags[wg], target, __ATOMIC_RELEASE, __HIP_MEMORY_SCOPE_AGENT);
      while (__hip_atomic_load(genp, __ATOMIC_ACQUIRE, __HIP_MEMORY_SCOPE_AGENT) < target)
        __builtin_amdgcn_s_sleep(2);
    }
  }
  __threadfence();
  __syncthreads();
}

// ---- generic 64x16 tile of  C = A @ B^T  (split-bf16 3-pass) --------------
// wave w returns rows row0 + w*16 + (lane>>4)*4 + e, col = col0 + (lane&15)
__device__ __forceinline__ v4f tile_xwT(const u16* Ah, const u16* Al, size_t lda, int nks,
                                        const u16* Bh, const u16* Bl, size_t ldb,
                                        int row0, int brow0, v4f* red){
  int tid = threadIdx.x, w = tid >> 6, lane = tid & 63;
  v4f acc[4];
  #pragma unroll
  for (int i=0;i<4;i++) acc[i] = (v4f){0.f,0.f,0.f,0.f};
  for (int ks = w; ks < nks; ks += 4){
    int k0 = ks * 32;
    v8s bh = ldfrag(Bh, ldb, brow0, k0);
    v8s bl = ldfrag(Bl, ldb, brow0, k0);
    #pragma unroll
    for (int rt=0; rt<4; rt++){
      v8s a  = ldfrag(Ah, lda, row0 + rt*16, k0);
      v8s al = ldfrag(Al, lda, row0 + rt*16, k0);
      acc[rt] = MFMA_(a,  bh, acc[rt]);
      acc[rt] = MFMA_(al, bh, acc[rt]);
      acc[rt] = MFMA_(a,  bl, acc[rt]);
    }
  }
  __syncthreads();
  red[(0*4+w)*64+lane]=acc[0]; red[(1*4+w)*64+lane]=acc[1];
  red[(2*4+w)*64+lane]=acc[2]; red[(3*4+w)*64+lane]=acc[3];
  __syncthreads();
  v4f g = red[(w*4+0)*64+lane];
  g += red[(w*4+1)*64+lane]; g += red[(w*4+2)*64+lane]; g += red[(w*4+3)*64+lane];
  return g;
}

// ---- GRU gate tile: acc types {0:r, 1:z, 2:n_i, 3:n_h} --------------------
template<bool PAIR>
__device__ __forceinline__ void gru_tile(const u16* Axh, const u16* Axl, size_t ldx, int nkx,
                                         const u16* Ahh, const u16* Ahl, size_t ldh, int nkh,
                                         const u16* Wi,  const u16* Wil, size_t ldwi,
                                         const u16* Wh,  const u16* Whl, size_t ldwh,
                                         int row0, int col0, v4f* red, v4f* gate){
  int tid = threadIdx.x, w = tid >> 6, lane = tid & 63;
  v4f acc[4][4];
  #pragma unroll
  for (int i=0;i<4;i++){
    #pragma unroll
    for (int j=0;j<4;j++) acc[i][j] = (v4f){0.f,0.f,0.f,0.f};
  }
  // input side (gi): types 0,1,2
  for (int ks = w; ks < nkx; ks += 4){
    int k0 = ks * 32;
    v8s br = ldfrag(Wi, ldwi,        col0, k0);
    v8s bz = ldfrag(Wi, ldwi,  512 + col0, k0);
    v8s bn = ldfrag(Wi, ldwi, 1024 + col0, k0);
    v8s brl, bzl, bnl;
    if (PAIR){ brl = ldfrag(Wil, ldwi, col0, k0); bzl = ldfrag(Wil, ldwi, 512+col0, k0); bnl = ldfrag(Wil, ldwi, 1024+col0, k0); }
    #pragma unroll
    for (int rt=0; rt<4; rt++){
      v8s a = ldfrag(Axh, ldx, row0 + rt*16, k0);
      acc[rt][0] = MFMA_(a, br, acc[rt][0]);
      acc[rt][1] = MFMA_(a, bz, acc[rt][1]);
      acc[rt][2] = MFMA_(a, bn, acc[rt][2]);
      if (PAIR){
        v8s al = ldfrag(Axl, ldx, row0 + rt*16, k0);
        acc[rt][0] = MFMA_(al, br, acc[rt][0]); acc[rt][0] = MFMA_(a, brl, acc[rt][0]);
        acc[rt][1] = MFMA_(al, bz, acc[rt][1]); acc[rt][1] = MFMA_(a, bzl, acc[rt][1]);
        acc[rt][2] = MFMA_(al, bn, acc[rt][2]); acc[rt][2] = MFMA_(a, bnl, acc[rt][2]);
      }
    }
  }
  // hidden side (gh): types 0,1,3
  for (int ks = w; ks < nkh; ks += 4){
    int k0 = ks * 32;
    v8s br = ldfrag(Wh, ldwh,        col0, k0);
    v8s bz = ldfrag(Wh, ldwh,  512 + col0, k0);
    v8s bn = ldfrag(Wh, ldwh, 1024 + col0, k0);
    v8s brl, bzl, bnl;
    if (PAIR){ brl = ldfrag(Whl, ldwh, col0, k0); bzl = ldfrag(Whl, ldwh, 512+col0, k0); bnl = ldfrag(Whl, ldwh, 1024+col0, k0); }
    #pragma unroll
    for (int rt=0; rt<4; rt++){
      v8s a = ldfrag(Ahh, ldh, row0 + rt*16, k0);
      acc[rt][0] = MFMA_(a, br, acc[rt][0]);
      acc[rt][1] = MFMA_(a, bz, acc[rt][1]);
      acc[rt][3] = MFMA_(a, bn, acc[rt][3]);
      if (PAIR){
        v8s al = ldfrag(Ahl, ldh, row0 + rt*16, k0);
        acc[rt][0] = MFMA_(al, br, acc[rt][0]); acc[rt][0] = MFMA_(a, brl, acc[rt][0]);
        acc[rt][1] = MFMA_(al, bz, acc[rt][1]); acc[rt][1] = MFMA_(a, bzl, acc[rt][1]);
        acc[rt][3] = MFMA_(al, bn, acc[rt][3]); acc[rt][3] = MFMA_(a, bnl, acc[rt][3]);
      }
    }
  }
  // cross-wave reduce (4 rounds, 16KB LDS reuse)
  #pragma unroll
  for (int ty=0; ty<4; ty++){
    __syncthreads();
    red[(0*4+w)*64+lane]=acc[0][ty]; red[(1*4+w)*64+lane]=acc[1][ty];
    red[(2*4+w)*64+lane]=acc[2][ty]; red[(3*4+w)*64+lane]=acc[3][ty];
    __syncthreads();
    v4f g = red[(w*4+0)*64+lane];
    g += red[(w*4+1)*64+lane]; g += red[(w*4+2)*64+lane]; g += red[(w*4+3)*64+lane];
    gate[ty] = g;
  }
}

__device__ __forceinline__ void gru_combine(const v4f* gate, const float* bih, const float* bhh,
                                            const u16* Hph, const u16* Hpl,
                                            u16* Hnh, u16* Hnl, u16* encw, int t,
                                            int row0, int col0){
  int tid = threadIdx.x, w = tid >> 6, lane = tid & 63;
  int col  = col0 + (lane & 15);
  int rowb = row0 + w*16 + ((lane >> 4) << 2);
  float bir = bih[col], biz = bih[512+col], bin = bih[1024+col];
  float bhr = bhh[col], bhz = bhh[512+col], bhn = bhh[1024+col];
  #pragma unroll
  for (int e=0; e<4; e++){
    int row = rowb + e;
    float r = sigm(gate[0][e] + bir + bhr);
    float z = sigm(gate[1][e] + biz + bhz);
    float n = tanh_f(gate[2][e] + bin + r * (gate[3][e] + bhn));
    float hp = bf2f(Hph[(size_t)row*512 + col]);
    if (Hpl) hp += bf2f(Hpl[(size_t)row*512 + col]);
    float hv = (1.f - z) * n + z * hp;
    if (Hnl) splitstore(&Hnh[(size_t)row*512+col], &Hnl[(size_t)row*512+col], hv);
    else Hnh[(size_t)row*512+col] = f2bf(hv);
    if (encw) encw[((size_t)row*256 + t)*512 + col] = f2bf(hv);
  }
}

__device__ __forceinline__ float blk_max(float v, float* sred){
  #pragma unroll
  for (int off=32; off>0; off>>=1) v = fmaxf(v, __shfl_xor(v, off, 64));
  __syncthreads();
  if ((threadIdx.x & 63) == 0) sred[threadIdx.x >> 6] = v;
  __syncthreads();
  return fmaxf(fmaxf(sred[0], sred[1]), fmaxf(sred[2], sred[3]));
}
__device__ __forceinline__ float blk_sum(float v, float* sred){
  #pragma unroll
  for (int off=32; off>0; off>>=1) v += __shfl_xor(v, off, 64);
  __syncthreads();
  if ((threadIdx.x & 63) == 0) sred[threadIdx.x >> 6] = v;
  __syncthreads();
  return sred[0] + sred[1] + sred[2] + sred[3];
}

#define DECOUT_OFF 0
#define DECHID_OFF 1228800      // 128*32*300
#define ATTN_OFF   1359872      // + 2*128*512

__global__ void __launch_bounds__(TPB, 1) traffic_kernel(KArgs A){
  __shared__ v4f red[4*4*64];   // 16KB reduce scratch
  __shared__ float sred[4];
  const int tid = threadIdx.x;
  const int wg  = blockIdx.x;
  const size_t gtid = (size_t)wg * TPB + tid;
  const size_t P = (size_t)NWG * TPB;
  unsigned bt = 0;

  // ================= Phase 0: weight conversion / padding / zeroing ========
  for (size_t i=gtid; i<2UL*1536*512; i+=P){ A.eWih[i]=f2bf(A.eWih_f[i]); A.eWhh[i]=f2bf(A.eWhh_f[i]); }
  for (size_t i=gtid; i<128UL*256*512; i+=P) A.xhi[i] = f2bf(A.x[i]);
  for (size_t i=gtid; i<1536UL*320; i+=P){
    size_t r=i/320, c=i%320;
    float v = (c<300)? A.dWih0_f[r*300+c] : 0.f;
    splitstore(&A.dWih0h[i], &A.dWih0l[i], v);
  }
  for (size_t i=gtid; i<1536UL*512; i+=P) splitstore(&A.dWih1h[i], &A.dWih1l[i], A.dWih1_f[i]);
  for (size_t i=gtid; i<2UL*1536*512; i+=P) splitstore(&A.dWhhh[i], &A.dWhhl[i], A.dWhh_f[i]);
  for (size_t i=gtid; i<256UL*512; i+=P){ size_t r=i>>9, c=i&511; splitstore(&A.Wwhh[i], &A.Wwhl[i], A.aWw_f[r*812+300+c]); }
  for (size_t i=gtid; i<256UL*320; i+=P){ size_t r=i/320, c=i%320; float v=(c<300)? A.aWw_f[r*812+c]:0.f; splitstore(&A.Wwxh[i], &A.Wwxl[i], v); }
  for (size_t i=gtid; i<304UL*512; i+=P){ size_t r=i>>9, c=i&511; float v=(r<300)? A.aCw_f[r*812+300+c]:0.f; splitstore(&A.Wchh[i], &A.Wchl[i], v); }
  for (size_t i=gtid; i<304UL*320; i+=P){ size_t r=i/320, c=i%320; float v=(r<300&&c<300)? A.aCw_f[r*812+c]:0.f; splitstore(&A.Wcxh[i], &A.Wcxl[i], v); }
  for (size_t i=gtid; i<304UL*512; i+=P){ size_t r=i>>9, c=i&511; float v=(r<300)? A.o1w_f[r*512+c]:0.f; splitstore(&A.o1wh[i], &A.o1wl[i], v); }
  for (size_t i=gtid; i<304UL*320; i+=P){ size_t r=i/320, c=i%320; float v=(r<300&&c<300)? A.o2w_f[r*300+c]:0.f; splitstore(&A.o2wh[i], &A.o2wl[i], v); }
  for (size_t i=gtid; i<32UL*128*320; i+=P){
    size_t sb=i/320, c=i%320, s2=sb>>7, b=sb&127;
    float v = (c<300)? A.target[(b*33+s2)*300 + c] : 0.f;
    splitstore(&A.xth[i], &A.xtl[i], v);
  }
  for (size_t i=gtid; i<65536; i+=P){ A.h0hi[i]=0; A.h1hi[i]=0; }
  for (size_t i=gtid; i<128UL*320; i+=P){ A.xch[i]=0; A.xcl[i]=0; A.o1h[i]=0; A.o1l[i]=0; }
  gbar(A.flags, A.genp, ++bt);

  // ================= Phase 0b: precompute xt-side attn linears =============
  for (int tl = wg; tl < 1024; tl += NWG){        // preW: (32*128) x 256
    int rb = tl >> 4, cb = tl & 15;
    int row0 = rb*64, col0 = cb*16;
    v4f g = tile_xwT(A.xth, A.xtl, 320, 10, A.Wwxh, A.Wwxl, 320, row0, col0, red);
    int w = tid>>6, lane = tid&63;
    int col = col0 + (lane&15), rowb = row0 + w*16 + ((lane>>4)<<2);
    #pragma unroll
    for (int e=0;e<4;e++){ int row=rowb+e; A.preW[(size_t)row*256+col] = g[e] + A.aWb[col]; }
  }
  for (int tl = wg; tl < 1216; tl += NWG){        // preC: (32*128) x 304
    int rb = tl / 19, cb = tl % 19;
    int row0 = rb*64, col0 = cb*16;
    v4f g = tile_xwT(A.xth, A.xtl, 320, 10, A.Wcxh, A.Wcxl, 320, row0, col0, red);
    int w = tid>>6, lane = tid&63;
    int col = col0 + (lane&15), rowb = row0 + w*16 + ((lane>>4)<<2);
    #pragma unroll
    for (int e=0;e<4;e++){
      int row=rowb+e;
      float v = (col<300)? (g[e] + A.aCb[col]) : 0.f;
      A.preC[(size_t)row*320+col] = v;
    }
  }
  gbar(A.flags, A.genp, ++bt);

  // ================= Encoder: 2 layers x 256 steps =========================
  {
    int rb = wg >> 5, cb = wg & 31;
    int row0 = rb*64, col0 = cb*16;
    for (int l=0; l<2; l++){
      const u16* Wih = A.eWih + (size_t)l*1536*512;
      const u16* Whh = A.eWhh + (size_t)l*1536*512;
      const float* bih = A.ebih + l*1536;
      const float* bhh = A.ebhh + l*1536;
      for (int t=0; t<256; t++){
        const u16* Xb; size_t ldX; const u16* Hp; u16* Hn; u16* encw;
        if (l==0){ Xb = A.xhi + (size_t)t*512; ldX = 256*512;
                   Hp = A.h0hi + (size_t)t*65536; Hn = A.h0hi + (size_t)(t+1)*65536; encw = nullptr; }
        else     { Xb = A.h0hi + (size_t)(t+1)*65536; ldX = 512;
                   Hp = A.h1hi + (size_t)(t&1)*65536; Hn = A.h1hi + (size_t)((t+1)&1)*65536; encw = A.encout; }
        v4f gate[4];
        gru_tile<false>(Xb, nullptr, ldX, 16, Hp, nullptr, 512, 16,
                        Wih, nullptr, 512, Whh, nullptr, 512, row0, col0, red, gate);
        gru_combine(gate, bih, bhh, Hp, nullptr, Hn, nullptr, encw, t, row0, col0);
        gbar(A.flags, A.genp, ++bt);
      }
    }
  }

  // ================= Decoder init: h = enc_hidden ==========================
  for (size_t i=gtid; i<65536; i+=P){
    A.dh0h[i] = A.h0hi[(size_t)256*65536 + i]; A.dh0l[i] = 0;
    A.dh1h[i] = A.h1hi[i];                     A.dh1l[i] = 0;   // layer1 final in buf 0
  }
  gbar(A.flags, A.genp, ++bt);

  // ================= Decoder: 32 steps =====================================
  for (int s=0; s<32; s++){
    const u16* h0ph = A.dh0h + (size_t)(s&1)*65536;
    const u16* h0pl = A.dh0l + (size_t)(s&1)*65536;
    u16* h0nh = A.dh0h + (size_t)((s+1)&1)*65536;
    u16* h0nl = A.dh0l + (size_t)((s+1)&1)*65536;
    const u16* h1ph = A.dh1h + (size_t)(s&1)*65536;
    const u16* h1pl = A.dh1l + (size_t)(s&1)*65536;
    u16* h1nh = A.dh1h + (size_t)((s+1)&1)*65536;
    u16* h1nl = A.dh1l + (size_t)((s+1)&1)*65536;

    // S1: logits = preW[s] + h1 @ Wwh^T      (128 x 256)
    if (wg < 32){
      int rb = wg >> 4, cb = wg & 15;
      int row0 = rb*64, col0 = cb*16;
      v4f g = tile_xwT(h1ph, h1pl, 512, 16, A.Wwhh, A.Wwhl, 512, row0, col0, red);
      const float* pre = A.preW + (size_t)s*128*256;
      int w = tid>>6, lane = tid&63;
      int col = col0 + (lane&15), rowb = row0 + w*16 + ((lane>>4)<<2);
      #pragma unroll
      for (int e=0;e<4;e++){ int row=rowb+e; A.logits[(size_t)row*256+col] = g[e] + pre[(size_t)row*256+col]; }
    }
    gbar(A.flags, A.genp, ++bt);

    // S2: softmax rows -> aw, attn output
    {
      #pragma unroll
      for (int bi=0; bi<2; bi++){
        int b = wg*2 + bi;
        float v = A.logits[(size_t)b*256 + tid];
        float m = blk_max(v, sred);
        float e = __expf(v - m);
        float ssum = blk_sum(e, sred);
        float awv = e / ssum;
        A.aw[(size_t)b*256 + tid] = awv;
        A.out[ATTN_OFF + ((size_t)b*32 + s)*256 + tid] = awv;
      }
    }
    gbar(A.flags, A.genp, ++bt);

    // S3: wctx[b,h] = sum_t aw[b,t] * enc_out[b,t,h]
    {
      int b0 = wg*2, b1 = b0+1;
      float a00=0.f,a01=0.f,a10=0.f,a11=0.f;
      const float* aw0 = A.aw + (size_t)b0*256;
      const float* aw1 = A.aw + (size_t)b1*256;
      const u16* e0 = A.encout + (size_t)b0*256*512;
      const u16* e1 = A.encout + (size_t)b1*256*512;
      for (int t2=0; t2<256; t2++){
        float w0 = aw0[t2], w1 = aw1[t2];
        a00 += w0 * bf2f(e0[(size_t)t2*512 + tid]);
        a01 += w0 * bf2f(e0[(size_t)t2*512 + 256 + tid]);
        a10 += w1 * bf2f(e1[(size_t)t2*512 + tid]);
        a11 += w1 * bf2f(e1[(size_t)t2*512 + 256 + tid]);
      }
      splitstore(&A.wcth[(size_t)b0*512+tid],     &A.wctl[(size_t)b0*512+tid],     a00);
      splitstore(&A.wcth[(size_t)b0*512+256+tid], &A.wctl[(size_t)b0*512+256+tid], a01);
      splitstore(&A.wcth[(size_t)b1*512+tid],     &A.wctl[(size_t)b1*512+tid],     a10);
      splitstore(&A.wcth[(size_t)b1*512+256+tid], &A.wctl[(size_t)b1*512+256+tid], a11);
    }
    gbar(A.flags, A.genp, ++bt);

    // S4: xc = relu(preC[s] + wctx @ Wch^T)   (128 x 304, pads stay 0)
    if (wg < 38){
      int rb = wg / 19, cb = wg % 19;
      int row0 = rb*64, col0 = cb*16;
      v4f g = tile_xwT(A.wcth, A.wctl, 512, 16, A.Wchh, A.Wchl, 512, row0, col0, red);
      const float* pre = A.preC + (size_t)s*128*320;
      int w = tid>>6, lane = tid&63;
      int col = col0 + (lane&15), rowb = row0 + w*16 + ((lane>>4)<<2);
      #pragma unroll
      for (int e=0;e<4;e++){
        int row = rowb+e;
        float v = (col<300)? fmaxf(g[e] + pre[(size_t)row*320+col], 0.f) : 0.f;
        splitstore(&A.xch[(size_t)row*320+col], &A.xcl[(size_t)row*320+col], v);
      }
    }
    gbar(A.flags, A.genp, ++bt);

    // S5: GRU layer 0: h0' = gru(xc, h0)
    {
      int rb = wg >> 5, cb = wg & 31;
      int row0 = rb*64, col0 = cb*16;
      v4f gate[4];
      gru_tile<true>(A.xch, A.xcl, 320, 10, h0ph, h0pl, 512, 16,
                     A.dWih0h, A.dWih0l, 320, A.dWhhh, A.dWhhl, 512, row0, col0, red, gate);
      gru_combine(gate, A.dbih, A.dbhh, h0ph, h0pl, h0nh, h0nl, nullptr, 0, row0, col0);
    }
    gbar(A.flags, A.genp, ++bt);

    // S6: GRU layer 1: h1' = gru(h0', h1)
    {
      int rb = wg >> 5, cb = wg & 31;
      int row0 = rb*64, col0 = cb*16;
      v4f gate[4];
      gru_tile<true>(h0nh, h0nl, 512, 16, h1ph, h1pl, 512, 16,
                     A.dWih1h, A.dWih1l, 512,
                     A.dWhhh + (size_t)1536*512, A.dWhhl + (size_t)1536*512, 512,
                     row0, col0, red, gate);
      gru_combine(gate, A.dbih + 1536, A.dbhh + 1536, h1ph, h1pl, h1nh, h1nl, nullptr, 0, row0, col0);
    }
    gbar(A.flags, A.genp, ++bt);

    // S7: o1 = h1' @ out1^T + b1   (128 x 304)
    if (wg < 38){
      int rb = wg / 19, cb = wg % 19;
      int row0 = rb*64, col0 = cb*16;
      v4f g = tile_xwT(h1nh, h1nl, 512, 16, A.o1wh, A.o1wl, 512, row0, col0, red);
      int w = tid>>6, lane = tid&63;
      int col = col0 + (lane&15), rowb = row0 + w*16 + ((lane>>4)<<2);
      #pragma unroll
      for (int e=0;e<4;e++){
        int row = rowb+e;
        float v = (col<300)? (g[e] + A.o1b[col]) : 0.f;
        splitstore(&A.o1h[(size_t)row*320+col], &A.o1l[(size_t)row*320+col], v);
      }
    }
    gbar(A.flags, A.genp, ++bt);

    // S8: dec_out[:,s,:] = o1 @ out2^T + b2
    if (wg < 38){
      int rb = wg / 19, cb = wg % 19;
      int row0 = rb*64, col0 = cb*16;
      v4f g = tile_xwT(A.o1h, A.o1l, 320, 10, A.o2wh, A.o2wl, 320, row0, col0, red);
      int w = tid>>6, lane = tid&63;
      int col = col0 + (lane&15), rowb = row0 + w*16 + ((lane>>4)<<2);
      #pragma unroll
      for (int e=0;e<4;e++){
        int row = rowb+e;
        if (col < 300) A.out[DECOUT_OFF + ((size_t)row*32 + s)*300 + col] = g[e] + A.o2b[col];
      }
    }
    // no barrier needed before next step's S1 (h1' was barred after S6)
  }

  // ================= dec_hidden output (final h in buffer 0) ===============
  for (size_t i=gtid; i<65536; i+=P){
    A.out[DECHID_OFF + i]         = bf2f(A.dh0h[i]) + bf2f(A.dh0l[i]);
    A.out[DECHID_OFF + 65536 + i] = bf2f(A.dh1h[i]) + bf2f(A.dh1l[i]);
  }
}

// ===========================================================================
extern "C" void kernel_launch(void* const* d_in, const int* in_sizes, int n_in,
                              void* d_out, int out_size, void* d_ws, size_t ws_size,
                              hipStream_t stream){
  (void)in_sizes; (void)n_in; (void)out_size; (void)ws_size;
  KArgs A;
  A.x       = (const float*)d_in[0];  A.target = (const float*)d_in[1];
  A.eWih_f  = (const float*)d_in[2];  A.eWhh_f = (const float*)d_in[3];
  A.ebih    = (const float*)d_in[4];  A.ebhh   = (const float*)d_in[5];
  A.dWih0_f = (const float*)d_in[6];  A.dWih1_f= (const float*)d_in[7];
  A.dWhh_f  = (const float*)d_in[8];  A.dbih   = (const float*)d_in[9];
  A.dbhh    = (const float*)d_in[10];
  A.aWw_f   = (const float*)d_in[11]; A.aWb    = (const float*)d_in[12];
  A.aCw_f   = (const float*)d_in[13]; A.aCb    = (const float*)d_in[14];
  A.o1w_f   = (const float*)d_in[15]; A.o1b    = (const float*)d_in[16];
  A.o2w_f   = (const float*)d_in[17]; A.o2b    = (const float*)d_in[18];
  A.out = (float*)d_out;

  char* w = (char*)d_ws;
  size_t off = 0;
  auto alloc = [&](size_t bytes)->char*{
    char* p = w + off; off += (bytes + 255) & ~(size_t)255; return p;
  };
  char* barp = alloc(4096);
  A.flags = (unsigned*)barp;
  A.genp  = (unsigned*)(barp + 2048);
  A.eWih   = (u16*)alloc(2UL*1536*512*2);
  A.eWhh   = (u16*)alloc(2UL*1536*512*2);
  A.xhi    = (u16*)alloc(128UL*256*512*2);
  A.h0hi   = (u16*)alloc(257UL*128*512*2);
  A.h1hi   = (u16*)alloc(2UL*128*512*2);
  A.encout = A.xhi;   // alias: xhi only read in encoder layer 0, encout only written in layer 1
  A.dWih0h = (u16*)alloc(1536UL*320*2); A.dWih0l = (u16*)alloc(1536UL*320*2);
  A.dWih1h = (u16*)alloc(1536UL*512*2); A.dWih1l = (u16*)alloc(1536UL*512*2);
  A.dWhhh  = (u16*)alloc(2UL*1536*512*2); A.dWhhl = (u16*)alloc(2UL*1536*512*2);
  A.Wwhh   = (u16*)alloc(256UL*512*2);  A.Wwhl   = (u16*)alloc(256UL*512*2);
  A.Wwxh   = (u16*)alloc(256UL*320*2);  A.Wwxl   = (u16*)alloc(256UL*320*2);
  A.Wchh   = (u16*)alloc(304UL*512*2);  A.Wchl   = (u16*)alloc(304UL*512*2);
  A.Wcxh   = (u16*)alloc(304UL*320*2);  A.Wcxl   = (u16*)alloc(304UL*320*2);
  A.o1wh   = (u16*)alloc(304UL*512*2);  A.o1wl   = (u16*)alloc(304UL*512*2);
  A.o2wh   = (u16*)alloc(304UL*320*2);  A.o2wl   = (u16*)alloc(304UL*320*2);
  A.xth    = (u16*)alloc(32UL*128*320*2); A.xtl  = (u16*)alloc(32UL*128*320*2);
  A.preW   = (float*)alloc(32UL*128*256*4);
  A.preC   = (float*)alloc(32UL*128*320*4);
  A.dh0h   = (u16*)alloc(2UL*65536*2); A.dh0l = (u16*)alloc(2UL*65536*2);
  A.dh1h   = (u16*)alloc(2UL*65536*2); A.dh1l = (u16*)alloc(2UL*65536*2);
  A.logits = (float*)alloc(128UL*256*4);
  A.aw     = (float*)alloc(128UL*256*4);
  A.wcth   = (u16*)alloc(128UL*512*2); A.wctl = (u16*)alloc(128UL*512*2);
  A.xch    = (u16*)alloc(128UL*320*2); A.xcl  = (u16*)alloc(128UL*320*2);
  A.o1h    = (u16*)alloc(128UL*320*2); A.o1l  = (u16*)alloc(128UL*320*2);

  hipMemsetAsync(d_ws, 0, 4096, stream);   // reset barrier flags/gen each launch
  traffic_kernel<<<dim3(NWG), dim3(TPB), 0, stream>>>(A);
}